// Round 15
// baseline (734.505 us; speedup 1.0000x reference)
//
#include <hip/hip_runtime.h>
#include <cstdint>
#include <cstddef>

#define DEVI __device__ __forceinline__

typedef __attribute__((ext_vector_type(8))) short short8;
typedef __attribute__((ext_vector_type(4))) float floatx4;

constexpr int B_ = 2, T_ = 4096, D_ = 2048, H_ = 16, DH = 128;
constexpr int BT = B_ * T_;           // 8192
constexpr int C_ = 64, NC = T_ / C_;  // chunk size, num chunks (64)
constexpr int RSQ = 3 * D_;           // fused qkv row stride

DEVI float bf2f(ushort u){ union { uint32_t i; float f; } v; v.i = ((uint32_t)u) << 16; return v.f; }
DEVI ushort f2bf(float f){ union { float f; uint32_t i; } v; v.f = f; uint32_t r = v.i + 0x7fff + ((v.i >> 16) & 1); return (ushort)(r >> 16); }
DEVI float sigm(float x){ return 1.f / (1.f + __expf(-x)); }

DEVI void async_load16(const void* g, void* l){
  __builtin_amdgcn_global_load_lds((const __attribute__((address_space(1))) unsigned int*)g,
                                   (__attribute__((address_space(3))) unsigned int*)l, 16, 0, 0);
}
DEVI floatx4 mfma16(short8 a, short8 b, floatx4 c){
  return __builtin_amdgcn_mfma_f32_16x16x32_bf16(a, b, c, 0, 0, 0);
}

// ---------------------------------------------------------------- casts
__global__ __launch_bounds__(256) void cast_bf16_kernel(const float* __restrict__ x,
                                                        ushort* __restrict__ y, int n){
  int i = (blockIdx.x * 256 + threadIdx.x) * 8;
  if (i + 8 <= n){
    floatx4 a = *(const floatx4*)(x + i);
    floatx4 b = *(const floatx4*)(x + i + 4);
    short8 o;
    o[0]=(short)f2bf(a[0]); o[1]=(short)f2bf(a[1]); o[2]=(short)f2bf(a[2]); o[3]=(short)f2bf(a[3]);
    o[4]=(short)f2bf(b[0]); o[5]=(short)f2bf(b[1]); o[6]=(short)f2bf(b[2]); o[7]=(short)f2bf(b[3]);
    *(short8*)(y + i) = o;
  }
}

// Batched: 5 weight matrices [D][D] f32 -> [D][D] bf16 transposed, z selects.
__global__ __launch_bounds__(256) void transpose_cast5(
    const float* __restrict__ w0, const float* __restrict__ w1,
    const float* __restrict__ w2, const float* __restrict__ w3,
    const float* __restrict__ w4,
    ushort* __restrict__ o0, ushort* __restrict__ o1, ushort* __restrict__ o2,
    ushort* __restrict__ o3, ushort* __restrict__ o4){
  __shared__ float tile[32][33];
  const float* w; ushort* wt;
  switch (blockIdx.z){
    case 0: w = w0; wt = o0; break;
    case 1: w = w1; wt = o1; break;
    case 2: w = w2; wt = o2; break;
    case 3: w = w3; wt = o3; break;
    default: w = w4; wt = o4; break;
  }
  int bx = blockIdx.x, by = blockIdx.y;
  int tx = threadIdx.x & 31, ty = threadIdx.x >> 5;  // ty 0..7
  #pragma unroll
  for (int j = 0; j < 4; ++j)
    tile[ty + j*8][tx] = w[(size_t)(by*32 + ty + j*8) * D_ + bx*32 + tx];
  __syncthreads();
  #pragma unroll
  for (int j = 0; j < 4; ++j){
    int n = bx*32 + ty + j*8, k = by*32 + tx;
    wt[(size_t)n * D_ + k] = f2bf(tile[tx][ty + j*8]);
  }
}

// Wb [D][H] f32 -> WbT [H][D] bf16
__global__ __launch_bounds__(256) void cast_wbT(const float* __restrict__ Wb,
                                                ushort* __restrict__ WbT){
  int c = blockIdx.x * 256 + threadIdx.x;   // 0..D_-1
  #pragma unroll
  for (int h = 0; h < H_; ++h)
    WbT[h * D_ + c] = f2bf(Wb[(size_t)c * H_ + h]);
}

// ---------------- 256x256 8-phase bf16 GEMM (T1..T5): C = A @ Bt^T
// Requires M == 8192 (nbm == 32) and gridDim.x % 64 == 0.
// XCD mapping: each XCD owns an 8 x (cpx/8) RECTANGLE of tiles.
template<bool F32OUT>
__global__ __launch_bounds__(512) void gemm256k(const ushort* __restrict__ A,
                                                const ushort* __restrict__ Bt,
                                                void* __restrict__ Cv,
                                                int M, int N, int K){
  __shared__ __align__(16) ushort As[2][256 * 64];
  __shared__ __align__(16) ushort Bs[2][256 * 64];
  const int tid = threadIdx.x;
  const int w = tid >> 6, lane = tid & 63, l16 = lane & 15, lq = lane >> 4;
  const int wm = w >> 2, wn = w & 3;
  const int xcd = (int)blockIdx.x & 7, jb = (int)blockIdx.x >> 3;
  const int cpx = gridDim.x >> 3;                    // blocks per XCD
  const int ccols = cpx >> 3;                        // rectangle = 8 x ccols
  const int bm = ((xcd & 3) << 3) + (jb & 7);
  const int bn = (xcd >> 2) * ccols + (jb >> 3);
  const int srow = tid >> 3;                         // 0..63
  const int ce = ((tid & 7) ^ (srow & 7)) * 8;       // inverse-swizzled source col
  const ushort* Ab = A + (size_t)(bm*256 + srow) * K + ce;
  const ushort* Bb = Bt + (size_t)(bn*256 + srow) * K + ce;
  const int NT = K >> 6;

  floatx4 acc[8][4];
  #pragma unroll
  for (int i = 0; i < 8; ++i)
    #pragma unroll
    for (int jj = 0; jj < 4; ++jj) acc[i][jj] = (floatx4)0.f;

  auto stageA = [&](int kt, int buf){
    #pragma unroll
    for (int jj = 0; jj < 4; ++jj)
      async_load16(Ab + (size_t)(jj*64) * K + kt*64, (char*)&As[buf][0] + (jj*512 + tid)*16);
  };
  auto stageB = [&](int kt, int buf){
    #pragma unroll
    for (int jj = 0; jj < 4; ++jj)
      async_load16(Bb + (size_t)(jj*64) * K + kt*64, (char*)&Bs[buf][0] + (jj*512 + tid)*16);
  };
  auto frag = [&](const ushort* base, int row, int ks) -> short8 {
    int cB = (ks*64 + lq*16) ^ ((row & 7) << 4);
    return *(const short8*)(base + row*64 + (cB >> 1));
  };

  stageA(0, 0); stageB(0, 0);
  if (NT > 1){ stageA(1, 1); stageB(1, 1);
    asm volatile("s_waitcnt vmcnt(8)" ::: "memory");
  } else {
    asm volatile("s_waitcnt vmcnt(0)" ::: "memory");
  }
  __builtin_amdgcn_s_barrier();

  short8 afr[4][2], bfr[4][2];
  #pragma unroll 2
  for (int kt = 0; kt < NT; ++kt){
    const int buf = kt & 1;
    const ushort* pa = &As[buf][0];
    const ushort* pb = &Bs[buf][0];
    const bool st = (kt + 2 < NT);
    // phase 0
    #pragma unroll
    for (int mf = 0; mf < 4; ++mf){
      afr[mf][0] = frag(pa, wm*128 + mf*16 + l16, 0);
      afr[mf][1] = frag(pa, wm*128 + mf*16 + l16, 1);
    }
    #pragma unroll
    for (int nf = 0; nf < 2; ++nf){
      bfr[nf][0] = frag(pb, wn*64 + nf*16 + l16, 0);
      bfr[nf][1] = frag(pb, wn*64 + nf*16 + l16, 1);
    }
    __builtin_amdgcn_sched_barrier(0);
    __builtin_amdgcn_s_barrier();
    __builtin_amdgcn_sched_barrier(0);
    __builtin_amdgcn_s_setprio(1);
    #pragma unroll
    for (int mf = 0; mf < 4; ++mf)
      #pragma unroll
      for (int nf = 0; nf < 2; ++nf){
        acc[mf][nf] = mfma16(afr[mf][0], bfr[nf][0], acc[mf][nf]);
        acc[mf][nf] = mfma16(afr[mf][1], bfr[nf][1], acc[mf][nf]);
      }
    __builtin_amdgcn_s_setprio(0);
    __builtin_amdgcn_sched_barrier(0);
    __builtin_amdgcn_s_barrier();
    // phase 1
    #pragma unroll
    for (int nf = 2; nf < 4; ++nf){
      bfr[nf][0] = frag(pb, wn*64 + nf*16 + l16, 0);
      bfr[nf][1] = frag(pb, wn*64 + nf*16 + l16, 1);
    }
    __builtin_amdgcn_sched_barrier(0);
    __builtin_amdgcn_s_barrier();
    __builtin_amdgcn_sched_barrier(0);
    __builtin_amdgcn_s_setprio(1);
    #pragma unroll
    for (int mf = 0; mf < 4; ++mf)
      #pragma unroll
      for (int nf = 2; nf < 4; ++nf){
        acc[mf][nf] = mfma16(afr[mf][0], bfr[nf][0], acc[mf][nf]);
        acc[mf][nf] = mfma16(afr[mf][1], bfr[nf][1], acc[mf][nf]);
      }
    __builtin_amdgcn_s_setprio(0);
    __builtin_amdgcn_sched_barrier(0);
    __builtin_amdgcn_s_barrier();
    // phase 2
    #pragma unroll
    for (int mf = 0; mf < 4; ++mf){
      afr[mf][0] = frag(pa, wm*128 + (mf + 4)*16 + l16, 0);
      afr[mf][1] = frag(pa, wm*128 + (mf + 4)*16 + l16, 1);
    }
    if (st) stageB(kt + 2, buf);
    __builtin_amdgcn_sched_barrier(0);
    __builtin_amdgcn_s_barrier();
    __builtin_amdgcn_sched_barrier(0);
    __builtin_amdgcn_s_setprio(1);
    #pragma unroll
    for (int mf = 0; mf < 4; ++mf)
      #pragma unroll
      for (int nf = 2; nf < 4; ++nf){
        acc[mf + 4][nf] = mfma16(afr[mf][0], bfr[nf][0], acc[mf + 4][nf]);
        acc[mf + 4][nf] = mfma16(afr[mf][1], bfr[nf][1], acc[mf + 4][nf]);
      }
    __builtin_amdgcn_s_setprio(0);
    __builtin_amdgcn_sched_barrier(0);
    __builtin_amdgcn_s_barrier();
    // phase 3
    if (st) stageA(kt + 2, buf);
    __builtin_amdgcn_sched_barrier(0);
    __builtin_amdgcn_s_barrier();
    __builtin_amdgcn_s_setprio(1);
    #pragma unroll
    for (int mf = 0; mf < 4; ++mf)
      #pragma unroll
      for (int nf = 0; nf < 2; ++nf){
        acc[mf + 4][nf] = mfma16(afr[mf][0], bfr[nf][0], acc[mf + 4][nf]);
        acc[mf + 4][nf] = mfma16(afr[mf][1], bfr[nf][1], acc[mf + 4][nf]);
      }
    __builtin_amdgcn_s_setprio(0);
    __builtin_amdgcn_sched_barrier(0);
    if (st)                   asm volatile("s_waitcnt vmcnt(8)" ::: "memory");
    else if (kt + 1 < NT)     asm volatile("s_waitcnt vmcnt(0)" ::: "memory");
    __builtin_amdgcn_s_barrier();
  }

  #pragma unroll
  for (int mf = 0; mf < 8; ++mf)
    #pragma unroll
    for (int nf = 0; nf < 4; ++nf)
      #pragma unroll
      for (int r = 0; r < 4; ++r){
        int row = bm*256 + wm*128 + mf*16 + lq*4 + r;
        int col = bn*256 + wn*64 + nf*16 + l16;
        if (F32OUT) ((float*)Cv)[(size_t)row * N + col] = acc[mf][nf][r];
        else        ((ushort*)Cv)[(size_t)row * N + col] = f2bf(acc[mf][nf][r]);
      }
}

// ------------------- conv(K=4)+SiLU+l2norm; fused-qkv input (row stride RSQ)
__global__ __launch_bounds__(256) void conv3_kernel(
    const ushort* __restrict__ fqkv,
    const float* __restrict__ cwq, const float* __restrict__ cwk, const float* __restrict__ cwv,
    ushort* __restrict__ qn, ushort* __restrict__ kn, ushort* __restrict__ vc){
  const int blk = blockIdx.x;
  const int b  = (blk * 8) >> 12;          // / T_
  const int t0 = (blk * 8) & (T_ - 1);
  const int tid = threadIdx.x;
  const int ch0 = tid * 8;

  const float*  cws[3]  = {cwq, cwk, cwv};
  ushort*       dsts[3] = {qn, kn, vc};

  #pragma unroll
  for (int s = 0; s < 3; ++s){
    const ushort* src = fqkv + s * D_;
    floatx4 w[8];
    #pragma unroll
    for (int j = 0; j < 8; ++j) w[j] = *(const floatx4*)&cws[s][(ch0 + j) * 4];

    float xf[11][8];
    #pragma unroll
    for (int idx = 0; idx < 11; ++idx){
      int t = t0 - 3 + idx;
      short8 x = (t >= 0) ? *(const short8*)(src + (size_t)(b*T_ + t)*RSQ + ch0)
                          : (short8)(short)0;
      #pragma unroll
      for (int j = 0; j < 8; ++j) xf[idx][j] = bf2f((ushort)x[j]);
    }

    #pragma unroll
    for (int tt = 0; tt < 8; ++tt){
      float y[8];
      #pragma unroll
      for (int j = 0; j < 8; ++j){
        float a = xf[tt][j]*w[j][0] + xf[tt+1][j]*w[j][1]
                + xf[tt+2][j]*w[j][2] + xf[tt+3][j]*w[j][3];
        y[j] = a * sigm(a);
      }
      float scale = 1.f;
      if (s < 2){
        float ss = 0.f;
        #pragma unroll
        for (int j = 0; j < 8; ++j) ss += y[j]*y[j];
        #pragma unroll
        for (int m = 1; m < 16; m <<= 1) ss += __shfl_xor(ss, m);
        scale = rsqrtf(ss + 1e-6f);
        if (s == 0) scale *= 0.08838834764831845f;                 // * Dk^-0.5
      }
      short8 o;
      #pragma unroll
      for (int j = 0; j < 8; ++j) o[j] = (short)f2bf(y[j] * scale);
      *(short8*)(dsts[s] + (size_t)(b*T_ + t0 + tt)*D_ + ch0) = o;
    }
  }
}

// ---------------- beta = sigmoid(hb @ Wb): one wave per row, WbT bf16 [H][D]
__global__ __launch_bounds__(256) void beta_kernel(const ushort* __restrict__ hb,
                                                   const ushort* __restrict__ WbT,
                                                   float* __restrict__ beta){
  const int r = blockIdx.x * 4 + (threadIdx.x >> 6);
  const int lane = threadIdx.x & 63;
  float xf[32];
  #pragma unroll
  for (int i = 0; i < 4; ++i){
    short8 x = *(const short8*)(hb + (size_t)r * D_ + i*512 + lane*8);
    #pragma unroll
    for (int j = 0; j < 8; ++j) xf[i*8 + j] = bf2f((ushort)x[j]);
  }
  float res = 0.f;
  #pragma unroll
  for (int h = 0; h < H_; ++h){
    float s = 0.f;
    #pragma unroll
    for (int i = 0; i < 4; ++i){
      short8 wv = *(const short8*)(WbT + (size_t)h * D_ + i*512 + lane*8);
      #pragma unroll
      for (int j = 0; j < 8; ++j) s += xf[i*8 + j] * bf2f((ushort)wv[j]);
    }
    #pragma unroll
    for (int m = 1; m < 64; m <<= 1) s += __shfl_xor(s, m);
    if (lane == h) res = s;
  }
  if (lane < H_) beta[(size_t)r * H_ + lane] = sigm(res);
}

// -------- phase1: T=(I+L)^-1 via recursive doubling, W=-T b K, U=T b V
__global__ __launch_bounds__(256) void phase1(
    const ushort* __restrict__ kn, const ushort* __restrict__ vc, const float* __restrict__ beta,
    ushort* __restrict__ Wneg, ushort* __restrict__ U, ushort* __restrict__ KTg){
  __shared__ __align__(16) char smem[72960];
  ushort* Ks = (ushort*)smem;                          // [64*136]
  ushort* Xb = (ushort*)smem;                          // [64*72] overlays Ks
  ushort* KT = (ushort*)(smem + 17408);                // [128*72]
  ushort* VT = (ushort*)(smem + 17408 + 18432);        // [128*72]
  ushort* Xt = (ushort*)(smem + 17408 + 36864);        // [64*72]
  ushort* Pb = (ushort*)(smem + 17408 + 36864 + 9216); // [64*72]
  float*  bet = (float*)(smem + 17408 + 36864 + 18432);// [64]

  const int bx = blockIdx.x;
  const int c = bx & 63, h = (bx >> 6) & 15, b = bx >> 10;
  const int t0 = c * 64;
  const int tid = threadIdx.x, w = tid >> 6, lane = tid & 63, l16 = lane & 15, lq = lane >> 4;

  {
    int i = tid >> 2, d0 = (tid & 3) * 32;
    const ushort* kp = kn + (size_t)(b*T_ + t0 + i) * D_ + h*DH + d0;
    const ushort* vp = vc + (size_t)(b*T_ + t0 + i) * D_ + h*DH + d0;
    #pragma unroll
    for (int j = 0; j < 4; ++j){
      short8 kv = *(const short8*)(kp + j*8);
      short8 vv = *(const short8*)(vp + j*8);
      *(short8*)&Ks[i*136 + d0 + j*8] = kv;
      #pragma unroll
      for (int e = 0; e < 8; ++e){
        int d = d0 + j*8 + e;
        KT[d*72 + i] = (ushort)kv[e];
        VT[d*72 + i] = (ushort)vv[e];
      }
    }
    if (tid < 64) bet[tid] = beta[(size_t)(b*T_ + t0 + tid) * H_ + h];
  }
  __syncthreads();

  floatx4 accL[4];
  #pragma unroll
  for (int fn = 0; fn < 4; ++fn) accL[fn] = (floatx4)0.f;
  #pragma unroll
  for (int ks = 0; ks < 4; ++ks){
    short8 a = *(const short8*)&Ks[(w*16 + l16)*136 + ks*32 + lq*8];
    #pragma unroll
    for (int fn = 0; fn < 4; ++fn){
      short8 bb = *(const short8*)&Ks[(fn*16 + l16)*136 + ks*32 + lq*8];
      accL[fn] = mfma16(a, bb, accL[fn]);
    }
  }
  __syncthreads();  // Ks dead; Xb may overlay

  {
    size_t kb = (size_t)bx * (128 * 64);
    int d = tid >> 1, i0 = (tid & 1) * 32;
    #pragma unroll
    for (int j = 0; j < 4; ++j)
      *(short8*)(KTg + kb + d*64 + i0 + j*8) = *(const short8*)&KT[d*72 + i0 + j*8];
  }

  #pragma unroll
  for (int fn = 0; fn < 4; ++fn)
    #pragma unroll
    for (int r = 0; r < 4; ++r){
      int i = w*16 + lq*4 + r, j = fn*16 + l16;
      float v = (j < i) ? (-bet[i] * accL[fn][r]) : 0.f;
      ushort vb = f2bf(v);
      Xb[i*72 + j] = vb;
      Xt[j*72 + i] = vb;
      Pb[i*72 + j] = (i == j) ? f2bf(1.f) : vb;
    }
  __syncthreads();

  #pragma unroll 1
  for (int s = 0; s < 5; ++s){
    floatx4 accY[4];
    #pragma unroll
    for (int fn = 0; fn < 4; ++fn) accY[fn] = (floatx4)0.f;
    #pragma unroll
    for (int ks = 0; ks < 2; ++ks){
      short8 a = *(const short8*)&Xb[(w*16 + l16)*72 + ks*32 + lq*8];
      #pragma unroll
      for (int fn = 0; fn < 4; ++fn){
        short8 bb = *(const short8*)&Xt[(fn*16 + l16)*72 + ks*32 + lq*8];
        accY[fn] = mfma16(a, bb, accY[fn]);
      }
    }
    __syncthreads();
    #pragma unroll
    for (int fn = 0; fn < 4; ++fn)
      #pragma unroll
      for (int r = 0; r < 4; ++r){
        int i = w*16 + lq*4 + r, n = fn*16 + l16;
        ushort v = f2bf(accY[fn][r]);
        Xb[i*72 + n] = v;
        Xt[n*72 + i] = v;
      }
    __syncthreads();
    floatx4 accP[4];
    #pragma unroll
    for (int fn = 0; fn < 4; ++fn)
      #pragma unroll
      for (int r = 0; r < 4; ++r)
        accP[fn][r] = bf2f(Pb[(w*16 + lq*4 + r)*72 + fn*16 + l16]);
    #pragma unroll
    for (int ks = 0; ks < 2; ++ks){
      short8 a = *(const short8*)&Pb[(w*16 + l16)*72 + ks*32 + lq*8];
      #pragma unroll
      for (int fn = 0; fn < 4; ++fn){
        short8 bb = *(const short8*)&Xt[(fn*16 + l16)*72 + ks*32 + lq*8];
        accP[fn] = mfma16(a, bb, accP[fn]);
      }
    }
    #pragma unroll
    for (int fn = 0; fn < 4; ++fn)
      #pragma unroll
      for (int r = 0; r < 4; ++r)
        Pb[(w*16 + lq*4 + r)*72 + fn*16 + l16] = f2bf(accP[fn][r]);
    __syncthreads();
  }

  floatx4 accW[8], accU[8];
  #pragma unroll
  for (int fn = 0; fn < 8; ++fn){ accW[fn] = (floatx4)0.f; accU[fn] = (floatx4)0.f; }
  #pragma unroll
  for (int ks = 0; ks < 2; ++ks){
    short8 p = *(const short8*)&Pb[(w*16 + l16)*72 + ks*32 + lq*8];
    short8 a;
    #pragma unroll
    for (int e = 0; e < 8; ++e)
      a[e] = (short)f2bf(bf2f((ushort)p[e]) * bet[ks*32 + lq*8 + e]);
    #pragma unroll
    for (int fn = 0; fn < 8; ++fn){
      short8 bk = *(const short8*)&KT[(fn*16 + l16)*72 + ks*32 + lq*8];
      short8 bv = *(const short8*)&VT[(fn*16 + l16)*72 + ks*32 + lq*8];
      accW[fn] = mfma16(a, bk, accW[fn]);
      accU[fn] = mfma16(a, bv, accU[fn]);
    }
  }
  size_t base = (size_t)bx * (64 * 128);
  #pragma unroll
  for (int fn = 0; fn < 8; ++fn)
    #pragma unroll
    for (int r = 0; r < 4; ++r){
      int i = w*16 + lq*4 + r, d = fn*16 + l16;
      Wneg[base + i*128 + d] = f2bf(-accW[fn][r]);   // store -W
      U[base + i*128 + d]    = f2bf(accU[fn][r]);
    }
}

// -------- phase2 (sequential over chunks): v-split 4 ways, XCD co-location,
// DEPTH-2 register prefetch (loads for chunk c+2 issued during chunk c ->
// HBM latency fully hidden), 3 barriers/chunk (bar3 restored: protects
// post-bar2 reads of Ws/Qs/KTc from the NEXT chunk's staging overwrite).
__global__ __launch_bounds__(256) void phase2(
    const ushort* __restrict__ qn, const ushort* __restrict__ KTg,
    const ushort* __restrict__ Wneg, const ushort* __restrict__ U,
    ushort* __restrict__ UpT, ushort* __restrict__ Opart){
  __shared__ __align__(16) ushort Sb[2][32 * 136];  // S^T slice [v][k], dbuf
  __shared__ __align__(16) ushort Ws[64 * 136];
  __shared__ __align__(16) ushort Qs[64 * 136];
  __shared__ __align__(16) ushort KTc[128 * 72];
  __shared__ __align__(16) ushort Us[64 * 40];
  __shared__ __align__(16) ushort UT[32 * 72];

  const int bx = blockIdx.x;
  const int xcd = bx & 7, j = bx >> 3;
  const int bh = xcd * 4 + (j >> 2), vs = j & 3;
  const int b = bh >> 4, h = bh & 15;
  const int tid = threadIdx.x, w = tid >> 6, lane = tid & 63, l16 = lane & 15, lq = lane >> 4;

  for (int e = tid; e < 32*136; e += 256) Sb[0][e] = 0;

  floatx4 M[2][2];
  #pragma unroll
  for (int nf = 0; nf < 2; ++nf)
    #pragma unroll
    for (int kf = 0; kf < 2; ++kf) M[nf][kf] = (floatx4)0.f;

  const int si = tid >> 2, sd = (tid & 3) * 32;
  short8 rWa[4], rQa[4], rKa[4], rUa;    // prefetch set A (even chunks)
  short8 rWb[4], rQb[4], rKb[4], rUb;    // prefetch set B (odd chunks)

  auto loadrA = [&](int c){
    size_t cb = ((size_t)(bh*NC + c)) * (64 * 128);
    const ushort* wp = Wneg + cb + si*128 + sd;
    const ushort* qp = qn + ((size_t)(b*T_ + c*64 + si)) * D_ + h*DH + sd;
    const ushort* kp = KTg + cb + tid*32;
    #pragma unroll
    for (int j2 = 0; j2 < 4; ++j2){
      rWa[j2] = *(const short8*)(wp + j2*8);
      rQa[j2] = *(const short8*)(qp + j2*8);
      rKa[j2] = *(const short8*)(kp + j2*8);
    }
    rUa = *(const short8*)(U + cb + si*128 + vs*32 + (tid & 3)*8);
  };
  auto loadrB = [&](int c){
    size_t cb = ((size_t)(bh*NC + c)) * (64 * 128);
    const ushort* wp = Wneg + cb + si*128 + sd;
    const ushort* qp = qn + ((size_t)(b*T_ + c*64 + si)) * D_ + h*DH + sd;
    const ushort* kp = KTg + cb + tid*32;
    #pragma unroll
    for (int j2 = 0; j2 < 4; ++j2){
      rWb[j2] = *(const short8*)(wp + j2*8);
      rQb[j2] = *(const short8*)(qp + j2*8);
      rKb[j2] = *(const short8*)(kp + j2*8);
    }
    rUb = *(const short8*)(U + cb + si*128 + vs*32 + (tid & 3)*8);
  };

  // body for one chunk: stage already done + bar1 passed by caller.
  auto body = [&](int c, const ushort* Sc, ushort* Sn){
    floatx4 accU[2];
    #pragma unroll
    for (int fn = 0; fn < 2; ++fn)
      #pragma unroll
      for (int r = 0; r < 4; ++r)
        accU[fn][r] = bf2f(Us[(w*16 + lq*4 + r)*40 + fn*16 + l16]);
    #pragma unroll
    for (int ks = 0; ks < 4; ++ks){
      short8 a = *(const short8*)&Ws[(w*16 + l16)*136 + ks*32 + lq*8];
      #pragma unroll
      for (int fn = 0; fn < 2; ++fn){
        short8 bs = *(const short8*)&Sc[(fn*16 + l16)*136 + ks*32 + lq*8];
        accU[fn] = mfma16(a, bs, accU[fn]);
      }
    }
    #pragma unroll
    for (int fn = 0; fn < 2; ++fn)
      #pragma unroll
      for (int r = 0; r < 4; ++r)
        UT[(fn*16 + l16)*72 + w*16 + lq*4 + r] = f2bf(accU[fn][r]);
    __syncthreads();                     // bar2: UT visible

    size_t cb = ((size_t)(bh*NC + c)) * (64 * 128);
    {
      int nl = tid >> 3, i0 = (tid & 7) * 8;
      *(short8*)(UpT + cb + (size_t)(vs*32 + nl)*64 + i0) = *(const short8*)&UT[nl*72 + i0];
    }
    floatx4 accO[2];
    #pragma unroll
    for (int fn = 0; fn < 2; ++fn) accO[fn] = (floatx4)0.f;
    #pragma unroll
    for (int ks = 0; ks < 4; ++ks){
      short8 a = *(const short8*)&Qs[(w*16 + l16)*136 + ks*32 + lq*8];
      #pragma unroll
      for (int fn = 0; fn < 2; ++fn){
        short8 bs = *(const short8*)&Sc[(fn*16 + l16)*136 + ks*32 + lq*8];
        accO[fn] = mfma16(a, bs, accO[fn]);
      }
    }
    #pragma unroll
    for (int fn = 0; fn < 2; ++fn)
      #pragma unroll
      for (int r = 0; r < 4; ++r){
        int i = w*16 + lq*4 + r;
        Opart[cb + (size_t)i*128 + vs*32 + fn*16 + l16] = f2bf(accO[fn][r]);
      }
    #pragma unroll
    for (int ks = 0; ks < 2; ++ks){
      short8 a0 = *(const short8*)&UT[(l16)*72 + ks*32 + lq*8];
      short8 a1 = *(const short8*)&UT[(16 + l16)*72 + ks*32 + lq*8];
      #pragma unroll
      for (int kf = 0; kf < 2; ++kf){
        short8 bk = *(const short8*)&KTc[(w*32 + kf*16 + l16)*72 + ks*32 + lq*8];
        M[0][kf] = mfma16(a0, bk, M[0][kf]);
        M[1][kf] = mfma16(a1, bk, M[1][kf]);
      }
    }
    __syncthreads();                     // bar3: all Ws/Qs/KTc/UT/Sc reads done
    // rebuild into other buffer (disjoint from next chunk's staging regions)
    #pragma unroll
    for (int nf = 0; nf < 2; ++nf)
      #pragma unroll
      for (int kf = 0; kf < 2; ++kf)
        #pragma unroll
        for (int r = 0; r < 4; ++r)
          Sn[(nf*16 + lq*4 + r)*136 + w*32 + kf*16 + l16] = f2bf(M[nf][kf][r]);
  };

  loadrA(0); loadrB(1);
  #pragma unroll 1
  for (int c = 0; c < NC; c += 2){
    // even chunk c: Sc = Sb[0], Sn = Sb[1]
    #pragma unroll
    for (int j2 = 0; j2 < 4; ++j2){
      *(short8*)&Ws[si*136 + sd + j2*8] = rWa[j2];
      *(short8*)&Qs[si*136 + sd + j2*8] = rQa[j2];
      *(short8*)&KTc[(tid >> 1)*72 + (tid & 1)*32 + j2*8] = rKa[j2];
    }
    *(short8*)&Us[si*40 + (tid & 3)*8] = rUa;
    __syncthreads();                     // bar1
    if (c + 2 < NC) loadrA(c + 2);       // depth-2 prefetch
    body(c, &Sb[0][0], &Sb[1][0]);

    // odd chunk c+1: Sc = Sb[1], Sn = Sb[0]
    #pragma unroll
    for (int j2 = 0; j2 < 4; ++j2){
      *(short8*)&Ws[si*136 + sd + j2*8] = rWb[j2];
      *(short8*)&Qs[si*136 + sd + j2*8] = rQb[j2];
      *(short8*)&KTc[(tid >> 1)*72 + (tid & 1)*32 + j2*8] = rKb[j2];
    }
    *(short8*)&Us[si*40 + (tid & 3)*8] = rUb;
    __syncthreads();                     // bar1
    if (c + 3 < NC) loadrB(c + 3);       // depth-2 prefetch
    body(c + 1, &Sb[1][0], &Sb[0][0]);
  }
}

// -------- phase3 (parallel): O = Opart + tril(Q K^T) U', rmsnorm, gate
__global__ __launch_bounds__(256) void phase3(
    const ushort* __restrict__ qn, const ushort* __restrict__ kn,
    const ushort* __restrict__ UpT, const ushort* __restrict__ Opart,
    const ushort* g, const float* __restrict__ norm_w,
    ushort* og){
  __shared__ __align__(16) ushort Qs[64 * 136];
  __shared__ __align__(16) ushort Ks[64 * 136];
  __shared__ __align__(16) ushort UTs[128 * 72];
  __shared__ __align__(16) ushort Os[64 * 136];
  __shared__ __align__(16) ushort Gs[64 * 136];
  __shared__ __align__(16) ushort Ab[64 * 72];
  __shared__ float nw[128];

  const int bx = blockIdx.x;
  const int c = bx & 63, h = (bx >> 6) & 15, b = bx >> 10;
  const int t0 = c * 64;
  const int tid = threadIdx.x, w = tid >> 6, lane = tid & 63, l16 = lane & 15, lq = lane >> 4;
  const size_t cb = (size_t)bx * (64 * 128);

  {
    int i = tid >> 2, d0 = (tid & 3) * 32;
    const ushort* qp = qn + (size_t)(b*T_ + t0 + i) * D_ + h*DH + d0;
    const ushort* kp = kn + (size_t)(b*T_ + t0 + i) * D_ + h*DH + d0;
    const ushort* gp = g  + (size_t)(b*T_ + t0 + i) * D_ + h*DH + d0;
    const ushort* op = Opart + cb + i*128 + d0;
    #pragma unroll
    for (int j = 0; j < 4; ++j){
      *(short8*)&Qs[i*136 + d0 + j*8] = *(const short8*)(qp + j*8);
      *(short8*)&Ks[i*136 + d0 + j*8] = *(const short8*)(kp + j*8);
      *(short8*)&Gs[i*136 + d0 + j*8] = *(const short8*)(gp + j*8);
      *(short8*)&Os[i*136 + d0 + j*8] = *(const short8*)(op + j*8);
    }
    int n = tid >> 1, i0 = (tid & 1) * 32;
    #pragma unroll
    for (int j = 0; j < 4; ++j)
      *(short8*)&UTs[n*72 + i0 + j*8] = *(const short8*)(UpT + cb + n*64 + i0 + j*8);
    if (tid < 128) nw[tid] = norm_w[tid];
  }
  __syncthreads();

  floatx4 accA[4];
  #pragma unroll
  for (int fn = 0; fn < 4; ++fn) accA[fn] = (floatx4)0.f;
  #pragma unroll
  for (int ks = 0; ks < 4; ++ks){
    short8 a = *(const short8*)&Qs[(w*16 + l16)*136 + ks*32 + lq*8];
    #pragma unroll
    for (int fn = 0; fn < 4; ++fn){
      short8 bb = *(const short8*)&Ks[(fn*16 + l16)*136 + ks*32 + lq*8];
      accA[fn] = mfma16(a, bb, accA[fn]);
    }
  }
  #pragma unroll
  for (int fn = 0; fn < 4; ++fn)
    #pragma unroll
    for (int r = 0; r < 4; ++r){
      int i = w*16 + lq*4 + r, j = fn*16 + l16;
      Ab[i*72 + j] = f2bf((j <= i) ? accA[fn][r] : 0.f);
    }
  __syncthreads();

  floatx4 accO[8];
  #pragma unroll
  for (int fn = 0; fn < 8; ++fn)
    #pragma unroll
    for (int r = 0; r < 4; ++r)
      accO[fn][r] = bf2f(Os[(w*16 + lq*4 + r)*136 + fn*16 + l16]);
  #pragma unroll
  for (int ks = 0; ks < 2; ++ks){
    short8 a = *(const short8*)&Ab[(w*16 + l16)*72 + ks*32 + lq*8];
    #pragma unroll
    for (int fn = 0; fn < 8; ++fn){
      short8 bu = *(const short8*)&UTs[(fn*16 + l16)*72 + ks*32 + lq*8];
      accO[fn] = mfma16(a, bu, accO[fn]);
    }
  }
  #pragma unroll
  for (int r = 0; r < 4; ++r){
    float ss = 0.f;
    #pragma unroll
    for (int fn = 0; fn < 8; ++fn) ss += accO[fn][r] * accO[fn][r];
    #pragma unroll
    for (int m = 1; m < 16; m <<= 1) ss += __shfl_xor(ss, m);
    float rms = rsqrtf(ss * (1.f / 128.f) + 1e-5f);
    int i = w*16 + lq*4 + r;
    #pragma unroll
    for (int fn = 0; fn < 8; ++fn){
      int d = fn*16 + l16;
      float gv = bf2f(Gs[i*136 + d]);
      float o = accO[fn][r] * rms * nw[d] * sigm(gv);
      og[(size_t)(b*T_ + t0 + i) * D_ + h*DH + d] = f2bf(o);
    }
  }
}

// ---------------------------------------------------------------- launcher
extern "C" void kernel_launch(void* const* d_in, const int* in_sizes, int n_in,
                              void* d_out, int out_size, void* d_ws, size_t ws_size,
                              hipStream_t stream){
  const float* hidden = (const float*)d_in[0];
  const float* Wq = (const float*)d_in[5];
  const float* Wk = (const float*)d_in[6];
  const float* Wv = (const float*)d_in[7];
  const float* Wo = (const float*)d_in[8];
  const float* Wg = (const float*)d_in[9];
  const float* Wb = (const float*)d_in[10];
  const float* cwq = (const float*)d_in[11];
  const float* cwk = (const float*)d_in[12];
  const float* cwv = (const float*)d_in[13];
  const float* nw  = (const float*)d_in[14];

  char* ws = (char*)d_ws;
  size_t off = 0;
  auto alloc = [&](size_t bytes){ void* p = ws + off; off += (bytes + 255) & ~(size_t)255; return p; };
  const size_t SZ = (size_t)BT * D_ * 2;          // 32 MiB bf16 tensor
  ushort* hb   = (ushort*)alloc(SZ);              // hidden bf16 -> Opart
  ushort* wqT  = (ushort*)alloc((size_t)D_*D_*2); // wqT|wkT|wvT contiguous = fused B
  ushort* wkT  = (ushort*)alloc((size_t)D_*D_*2);
  ushort* wvT  = (ushort*)alloc((size_t)D_*D_*2);
  ushort* wgT  = (ushort*)alloc((size_t)D_*D_*2);
  ushort* woT  = (ushort*)alloc((size_t)D_*D_*2);
  ushort* wbT  = (ushort*)alloc((size_t)H_*D_*2);
  ushort* fqkv = (ushort*)alloc(3*SZ);            // fused [BT][3D] -> gpre|Wneg|U
  ushort* kn   = (ushort*)alloc(SZ);
  ushort* vcv  = (ushort*)alloc(SZ);              // -> UpT after phase1
  float*  beta = (float*)alloc((size_t)BT * H_ * 4);
  (void)in_sizes; (void)n_in; (void)out_size;
  if (off > ws_size) return;                      // ws too small -> clean absmax fail

  // d_out (64 MiB f32): first half = bf16 qn scratch, second half = KTg.
  ushort* qn  = (ushort*)d_out;
  ushort* KTg = (ushort*)d_out + (size_t)BT * D_;

  cast_bf16_kernel<<<8192, 256, 0, stream>>>(hidden, hb, BT * D_);
  transpose_cast5<<<dim3(64, 64, 5), 256, 0, stream>>>(Wq, Wk, Wv, Wg, Wo,
                                                       wqT, wkT, wvT, wgT, woT);
  cast_wbT<<<D_/256, 256, 0, stream>>>(Wb, wbT);

  // Fused QKV projection: C[8192][6144] = hb @ [wqT;wkT;wvT]^T
  {
    const int NWG = (BT / 256) * (RSQ / 256);     // 768 (cpx=96, rect 8x12)
    gemm256k<false><<<NWG, 512, 0, stream>>>(hb, wqT, fqkv, BT, RSQ, D_);
  }

  conv3_kernel<<<BT/8, 256, 0, stream>>>(fqkv, cwq, cwk, cwv, qn, kn, vcv);
  beta_kernel<<<BT/4, 256, 0, stream>>>(hb, wbT, beta);

  // fqkv fully dead after conv: reuse as gpre | Wneg | U
  ushort* gpre = fqkv;
  ushort* Wneg = fqkv + (size_t)BT * D_;
  ushort* Ubuf = fqkv + (size_t)2 * BT * D_;
  {
    const int NWG = (BT / 256) * (D_ / 256);      // 256 (cpx=32, rect 8x4)
    gemm256k<false><<<NWG, 512, 0, stream>>>(hb, wgT, gpre, BT, D_, D_);
  }

  ushort* Opart = hb;     // dead after proj GEMMs

  phase1<<<B_ * H_ * NC, 256, 0, stream>>>(kn, vcv, beta, Wneg, Ubuf, KTg);
  ushort* UpT = vcv;      // vcv dead after phase1
  phase2<<<B_ * H_ * 4, 256, 0, stream>>>(qn, KTg, Wneg, Ubuf, UpT, Opart);
  ushort* og = gpre;      // in-place gate (block reads its g-tile to LDS first)
  phase3<<<B_ * H_ * NC, 256, 0, stream>>>(qn, kn, UpT, Opart, gpre, nw, og);

  {
    const int NWG = (BT / 256) * (D_ / 256);      // 256 (cpx=32, rect 8x4)
    gemm256k<true><<<NWG, 512, 0, stream>>>(og, woT, (float*)d_out, BT, D_, D_);
  }
}

// Round 16
// 703.891 us; speedup vs baseline: 1.0435x; 1.0435x over previous
//
#include <hip/hip_runtime.h>
#include <cstdint>
#include <cstddef>

#define DEVI __device__ __forceinline__

typedef __attribute__((ext_vector_type(8))) short short8;
typedef __attribute__((ext_vector_type(4))) float floatx4;

constexpr int B_ = 2, T_ = 4096, D_ = 2048, H_ = 16, DH = 128;
constexpr int BT = B_ * T_;           // 8192
constexpr int C_ = 64, NC = T_ / C_;  // chunk size, num chunks (64)
constexpr int RSQ = 3 * D_;           // fused qkv row stride

DEVI float bf2f(ushort u){ union { uint32_t i; float f; } v; v.i = ((uint32_t)u) << 16; return v.f; }
DEVI ushort f2bf(float f){ union { float f; uint32_t i; } v; v.f = f; uint32_t r = v.i + 0x7fff + ((v.i >> 16) & 1); return (ushort)(r >> 16); }
DEVI float sigm(float x){ return 1.f / (1.f + __expf(-x)); }

DEVI void async_load16(const void* g, void* l){
  __builtin_amdgcn_global_load_lds((const __attribute__((address_space(1))) unsigned int*)g,
                                   (__attribute__((address_space(3))) unsigned int*)l, 16, 0, 0);
}
DEVI floatx4 mfma16(short8 a, short8 b, floatx4 c){
  return __builtin_amdgcn_mfma_f32_16x16x32_bf16(a, b, c, 0, 0, 0);
}

// ---------------------------------------------------------------- casts
__global__ __launch_bounds__(256) void cast_bf16_kernel(const float* __restrict__ x,
                                                        ushort* __restrict__ y, int n){
  int i = (blockIdx.x * 256 + threadIdx.x) * 8;
  if (i + 8 <= n){
    floatx4 a = *(const floatx4*)(x + i);
    floatx4 b = *(const floatx4*)(x + i + 4);
    short8 o;
    o[0]=(short)f2bf(a[0]); o[1]=(short)f2bf(a[1]); o[2]=(short)f2bf(a[2]); o[3]=(short)f2bf(a[3]);
    o[4]=(short)f2bf(b[0]); o[5]=(short)f2bf(b[1]); o[6]=(short)f2bf(b[2]); o[7]=(short)f2bf(b[3]);
    *(short8*)(y + i) = o;
  }
}

// Batched: 5 weight matrices [D][D] f32 -> [D][D] bf16 transposed, z selects.
__global__ __launch_bounds__(256) void transpose_cast5(
    const float* __restrict__ w0, const float* __restrict__ w1,
    const float* __restrict__ w2, const float* __restrict__ w3,
    const float* __restrict__ w4,
    ushort* __restrict__ o0, ushort* __restrict__ o1, ushort* __restrict__ o2,
    ushort* __restrict__ o3, ushort* __restrict__ o4){
  __shared__ float tile[32][33];
  const float* w; ushort* wt;
  switch (blockIdx.z){
    case 0: w = w0; wt = o0; break;
    case 1: w = w1; wt = o1; break;
    case 2: w = w2; wt = o2; break;
    case 3: w = w3; wt = o3; break;
    default: w = w4; wt = o4; break;
  }
  int bx = blockIdx.x, by = blockIdx.y;
  int tx = threadIdx.x & 31, ty = threadIdx.x >> 5;  // ty 0..7
  #pragma unroll
  for (int j = 0; j < 4; ++j)
    tile[ty + j*8][tx] = w[(size_t)(by*32 + ty + j*8) * D_ + bx*32 + tx];
  __syncthreads();
  #pragma unroll
  for (int j = 0; j < 4; ++j){
    int n = bx*32 + ty + j*8, k = by*32 + tx;
    wt[(size_t)n * D_ + k] = f2bf(tile[tx][ty + j*8]);
  }
}

// Wb [D][H] f32 -> WbT [H][D] bf16
__global__ __launch_bounds__(256) void cast_wbT(const float* __restrict__ Wb,
                                                ushort* __restrict__ WbT){
  int c = blockIdx.x * 256 + threadIdx.x;   // 0..D_-1
  #pragma unroll
  for (int h = 0; h < H_; ++h)
    WbT[h * D_ + c] = f2bf(Wb[(size_t)c * H_ + h]);
}

// ---------------- 256x256 8-phase bf16 GEMM (T1..T5): C = A @ Bt^T
// Requires M == 8192 (nbm == 32) and gridDim.x % 64 == 0.
// XCD mapping: each XCD owns an 8 x (cpx/8) RECTANGLE of tiles.
// No explicit lgkmcnt(0) drains — compiler emits counted lgkmcnt per
// data-dep (m97/m141 evidence). Safe: every frag read is consumed by
// same-phase MFMAs, so reads complete >=2 barriers before any staging
// overwrite of that region.
template<bool F32OUT>
__global__ __launch_bounds__(512) void gemm256k(const ushort* __restrict__ A,
                                                const ushort* __restrict__ Bt,
                                                void* __restrict__ Cv,
                                                int M, int N, int K){
  __shared__ __align__(16) ushort As[2][256 * 64];
  __shared__ __align__(16) ushort Bs[2][256 * 64];
  const int tid = threadIdx.x;
  const int w = tid >> 6, lane = tid & 63, l16 = lane & 15, lq = lane >> 4;
  const int wm = w >> 2, wn = w & 3;
  const int xcd = (int)blockIdx.x & 7, jb = (int)blockIdx.x >> 3;
  const int cpx = gridDim.x >> 3;                    // blocks per XCD
  const int ccols = cpx >> 3;                        // rectangle = 8 x ccols
  const int bm = ((xcd & 3) << 3) + (jb & 7);
  const int bn = (xcd >> 2) * ccols + (jb >> 3);
  const int srow = tid >> 3;                         // 0..63
  const int ce = ((tid & 7) ^ (srow & 7)) * 8;       // inverse-swizzled source col
  const ushort* Ab = A + (size_t)(bm*256 + srow) * K + ce;
  const ushort* Bb = Bt + (size_t)(bn*256 + srow) * K + ce;
  const int NT = K >> 6;

  floatx4 acc[8][4];
  #pragma unroll
  for (int i = 0; i < 8; ++i)
    #pragma unroll
    for (int jj = 0; jj < 4; ++jj) acc[i][jj] = (floatx4)0.f;

  auto stageA = [&](int kt, int buf){
    #pragma unroll
    for (int jj = 0; jj < 4; ++jj)
      async_load16(Ab + (size_t)(jj*64) * K + kt*64, (char*)&As[buf][0] + (jj*512 + tid)*16);
  };
  auto stageB = [&](int kt, int buf){
    #pragma unroll
    for (int jj = 0; jj < 4; ++jj)
      async_load16(Bb + (size_t)(jj*64) * K + kt*64, (char*)&Bs[buf][0] + (jj*512 + tid)*16);
  };
  auto frag = [&](const ushort* base, int row, int ks) -> short8 {
    int cB = (ks*64 + lq*16) ^ ((row & 7) << 4);
    return *(const short8*)(base + row*64 + (cB >> 1));
  };

  stageA(0, 0); stageB(0, 0);
  if (NT > 1){ stageA(1, 1); stageB(1, 1);
    asm volatile("s_waitcnt vmcnt(8)" ::: "memory");
  } else {
    asm volatile("s_waitcnt vmcnt(0)" ::: "memory");
  }
  __builtin_amdgcn_s_barrier();

  short8 afr[4][2], bfr[4][2];
  #pragma unroll 2
  for (int kt = 0; kt < NT; ++kt){
    const int buf = kt & 1;
    const ushort* pa = &As[buf][0];
    const ushort* pb = &Bs[buf][0];
    const bool st = (kt + 2 < NT);
    // phase 0
    #pragma unroll
    for (int mf = 0; mf < 4; ++mf){
      afr[mf][0] = frag(pa, wm*128 + mf*16 + l16, 0);
      afr[mf][1] = frag(pa, wm*128 + mf*16 + l16, 1);
    }
    #pragma unroll
    for (int nf = 0; nf < 2; ++nf){
      bfr[nf][0] = frag(pb, wn*64 + nf*16 + l16, 0);
      bfr[nf][1] = frag(pb, wn*64 + nf*16 + l16, 1);
    }
    __builtin_amdgcn_sched_barrier(0);
    __builtin_amdgcn_s_barrier();
    __builtin_amdgcn_sched_barrier(0);
    __builtin_amdgcn_s_setprio(1);
    #pragma unroll
    for (int mf = 0; mf < 4; ++mf)
      #pragma unroll
      for (int nf = 0; nf < 2; ++nf){
        acc[mf][nf] = mfma16(afr[mf][0], bfr[nf][0], acc[mf][nf]);
        acc[mf][nf] = mfma16(afr[mf][1], bfr[nf][1], acc[mf][nf]);
      }
    __builtin_amdgcn_s_setprio(0);
    __builtin_amdgcn_sched_barrier(0);
    __builtin_amdgcn_s_barrier();
    // phase 1
    #pragma unroll
    for (int nf = 2; nf < 4; ++nf){
      bfr[nf][0] = frag(pb, wn*64 + nf*16 + l16, 0);
      bfr[nf][1] = frag(pb, wn*64 + nf*16 + l16, 1);
    }
    __builtin_amdgcn_sched_barrier(0);
    __builtin_amdgcn_s_barrier();
    __builtin_amdgcn_sched_barrier(0);
    __builtin_amdgcn_s_setprio(1);
    #pragma unroll
    for (int mf = 0; mf < 4; ++mf)
      #pragma unroll
      for (int nf = 2; nf < 4; ++nf){
        acc[mf][nf] = mfma16(afr[mf][0], bfr[nf][0], acc[mf][nf]);
        acc[mf][nf] = mfma16(afr[mf][1], bfr[nf][1], acc[mf][nf]);
      }
    __builtin_amdgcn_s_setprio(0);
    __builtin_amdgcn_sched_barrier(0);
    __builtin_amdgcn_s_barrier();
    // phase 2
    #pragma unroll
    for (int mf = 0; mf < 4; ++mf){
      afr[mf][0] = frag(pa, wm*128 + (mf + 4)*16 + l16, 0);
      afr[mf][1] = frag(pa, wm*128 + (mf + 4)*16 + l16, 1);
    }
    if (st) stageB(kt + 2, buf);
    __builtin_amdgcn_sched_barrier(0);
    __builtin_amdgcn_s_barrier();
    __builtin_amdgcn_sched_barrier(0);
    __builtin_amdgcn_s_setprio(1);
    #pragma unroll
    for (int mf = 0; mf < 4; ++mf)
      #pragma unroll
      for (int nf = 2; nf < 4; ++nf){
        acc[mf + 4][nf] = mfma16(afr[mf][0], bfr[nf][0], acc[mf + 4][nf]);
        acc[mf + 4][nf] = mfma16(afr[mf][1], bfr[nf][1], acc[mf + 4][nf]);
      }
    __builtin_amdgcn_s_setprio(0);
    __builtin_amdgcn_sched_barrier(0);
    __builtin_amdgcn_s_barrier();
    // phase 3
    if (st) stageA(kt + 2, buf);
    __builtin_amdgcn_sched_barrier(0);
    __builtin_amdgcn_s_barrier();
    __builtin_amdgcn_s_setprio(1);
    #pragma unroll
    for (int mf = 0; mf < 4; ++mf)
      #pragma unroll
      for (int nf = 0; nf < 2; ++nf){
        acc[mf + 4][nf] = mfma16(afr[mf][0], bfr[nf][0], acc[mf + 4][nf]);
        acc[mf + 4][nf] = mfma16(afr[mf][1], bfr[nf][1], acc[mf + 4][nf]);
      }
    __builtin_amdgcn_s_setprio(0);
    __builtin_amdgcn_sched_barrier(0);
    if (st)                   asm volatile("s_waitcnt vmcnt(8)" ::: "memory");
    else if (kt + 1 < NT)     asm volatile("s_waitcnt vmcnt(0)" ::: "memory");
    __builtin_amdgcn_s_barrier();
  }

  #pragma unroll
  for (int mf = 0; mf < 8; ++mf)
    #pragma unroll
    for (int nf = 0; nf < 4; ++nf)
      #pragma unroll
      for (int r = 0; r < 4; ++r){
        int row = bm*256 + wm*128 + mf*16 + lq*4 + r;
        int col = bn*256 + wn*64 + nf*16 + l16;
        if (F32OUT) ((float*)Cv)[(size_t)row * N + col] = acc[mf][nf][r];
        else        ((ushort*)Cv)[(size_t)row * N + col] = f2bf(acc[mf][nf][r]);
      }
}

// ------------------- conv(K=4)+SiLU+l2norm; fused-qkv input (row stride RSQ)
__global__ __launch_bounds__(256) void conv3_kernel(
    const ushort* __restrict__ fqkv,
    const float* __restrict__ cwq, const float* __restrict__ cwk, const float* __restrict__ cwv,
    ushort* __restrict__ qn, ushort* __restrict__ kn, ushort* __restrict__ vc){
  const int blk = blockIdx.x;
  const int b  = (blk * 8) >> 12;          // / T_
  const int t0 = (blk * 8) & (T_ - 1);
  const int tid = threadIdx.x;
  const int ch0 = tid * 8;

  const float*  cws[3]  = {cwq, cwk, cwv};
  ushort*       dsts[3] = {qn, kn, vc};

  #pragma unroll
  for (int s = 0; s < 3; ++s){
    const ushort* src = fqkv + s * D_;
    floatx4 w[8];
    #pragma unroll
    for (int j = 0; j < 8; ++j) w[j] = *(const floatx4*)&cws[s][(ch0 + j) * 4];

    float xf[11][8];
    #pragma unroll
    for (int idx = 0; idx < 11; ++idx){
      int t = t0 - 3 + idx;
      short8 x = (t >= 0) ? *(const short8*)(src + (size_t)(b*T_ + t)*RSQ + ch0)
                          : (short8)(short)0;
      #pragma unroll
      for (int j = 0; j < 8; ++j) xf[idx][j] = bf2f((ushort)x[j]);
    }

    #pragma unroll
    for (int tt = 0; tt < 8; ++tt){
      float y[8];
      #pragma unroll
      for (int j = 0; j < 8; ++j){
        float a = xf[tt][j]*w[j][0] + xf[tt+1][j]*w[j][1]
                + xf[tt+2][j]*w[j][2] + xf[tt+3][j]*w[j][3];
        y[j] = a * sigm(a);
      }
      float scale = 1.f;
      if (s < 2){
        float ss = 0.f;
        #pragma unroll
        for (int j = 0; j < 8; ++j) ss += y[j]*y[j];
        #pragma unroll
        for (int m = 1; m < 16; m <<= 1) ss += __shfl_xor(ss, m);
        scale = rsqrtf(ss + 1e-6f);
        if (s == 0) scale *= 0.08838834764831845f;                 // * Dk^-0.5
      }
      short8 o;
      #pragma unroll
      for (int j = 0; j < 8; ++j) o[j] = (short)f2bf(y[j] * scale);
      *(short8*)(dsts[s] + (size_t)(b*T_ + t0 + tt)*D_ + ch0) = o;
    }
  }
}

// ---------------- beta = sigmoid(hb @ Wb): one wave per row, WbT bf16 [H][D]
__global__ __launch_bounds__(256) void beta_kernel(const ushort* __restrict__ hb,
                                                   const ushort* __restrict__ WbT,
                                                   float* __restrict__ beta){
  const int r = blockIdx.x * 4 + (threadIdx.x >> 6);
  const int lane = threadIdx.x & 63;
  float xf[32];
  #pragma unroll
  for (int i = 0; i < 4; ++i){
    short8 x = *(const short8*)(hb + (size_t)r * D_ + i*512 + lane*8);
    #pragma unroll
    for (int j = 0; j < 8; ++j) xf[i*8 + j] = bf2f((ushort)x[j]);
  }
  float res = 0.f;
  #pragma unroll
  for (int h = 0; h < H_; ++h){
    float s = 0.f;
    #pragma unroll
    for (int i = 0; i < 4; ++i){
      short8 wv = *(const short8*)(WbT + (size_t)h * D_ + i*512 + lane*8);
      #pragma unroll
      for (int j = 0; j < 8; ++j) s += xf[i*8 + j] * bf2f((ushort)wv[j]);
    }
    #pragma unroll
    for (int m = 1; m < 64; m <<= 1) s += __shfl_xor(s, m);
    if (lane == h) res = s;
  }
  if (lane < H_) beta[(size_t)r * H_ + lane] = sigm(res);
}

// -------- phase1: T=(I+L)^-1 via recursive doubling, W=-T b K, U=T b V
__global__ __launch_bounds__(256) void phase1(
    const ushort* __restrict__ kn, const ushort* __restrict__ vc, const float* __restrict__ beta,
    ushort* __restrict__ Wneg, ushort* __restrict__ U, ushort* __restrict__ KTg){
  __shared__ __align__(16) char smem[72960];
  ushort* Ks = (ushort*)smem;                          // [64*136]
  ushort* Xb = (ushort*)smem;                          // [64*72] overlays Ks
  ushort* KT = (ushort*)(smem + 17408);                // [128*72]
  ushort* VT = (ushort*)(smem + 17408 + 18432);        // [128*72]
  ushort* Xt = (ushort*)(smem + 17408 + 36864);        // [64*72]
  ushort* Pb = (ushort*)(smem + 17408 + 36864 + 9216); // [64*72]
  float*  bet = (float*)(smem + 17408 + 36864 + 18432);// [64]

  const int bx = blockIdx.x;
  const int c = bx & 63, h = (bx >> 6) & 15, b = bx >> 10;
  const int t0 = c * 64;
  const int tid = threadIdx.x, w = tid >> 6, lane = tid & 63, l16 = lane & 15, lq = lane >> 4;

  {
    int i = tid >> 2, d0 = (tid & 3) * 32;
    const ushort* kp = kn + (size_t)(b*T_ + t0 + i) * D_ + h*DH + d0;
    const ushort* vp = vc + (size_t)(b*T_ + t0 + i) * D_ + h*DH + d0;
    #pragma unroll
    for (int j = 0; j < 4; ++j){
      short8 kv = *(const short8*)(kp + j*8);
      short8 vv = *(const short8*)(vp + j*8);
      *(short8*)&Ks[i*136 + d0 + j*8] = kv;
      #pragma unroll
      for (int e = 0; e < 8; ++e){
        int d = d0 + j*8 + e;
        KT[d*72 + i] = (ushort)kv[e];
        VT[d*72 + i] = (ushort)vv[e];
      }
    }
    if (tid < 64) bet[tid] = beta[(size_t)(b*T_ + t0 + tid) * H_ + h];
  }
  __syncthreads();

  floatx4 accL[4];
  #pragma unroll
  for (int fn = 0; fn < 4; ++fn) accL[fn] = (floatx4)0.f;
  #pragma unroll
  for (int ks = 0; ks < 4; ++ks){
    short8 a = *(const short8*)&Ks[(w*16 + l16)*136 + ks*32 + lq*8];
    #pragma unroll
    for (int fn = 0; fn < 4; ++fn){
      short8 bb = *(const short8*)&Ks[(fn*16 + l16)*136 + ks*32 + lq*8];
      accL[fn] = mfma16(a, bb, accL[fn]);
    }
  }
  __syncthreads();  // Ks dead; Xb may overlay

  {
    size_t kb = (size_t)bx * (128 * 64);
    int d = tid >> 1, i0 = (tid & 1) * 32;
    #pragma unroll
    for (int j = 0; j < 4; ++j)
      *(short8*)(KTg + kb + d*64 + i0 + j*8) = *(const short8*)&KT[d*72 + i0 + j*8];
  }

  #pragma unroll
  for (int fn = 0; fn < 4; ++fn)
    #pragma unroll
    for (int r = 0; r < 4; ++r){
      int i = w*16 + lq*4 + r, j = fn*16 + l16;
      float v = (j < i) ? (-bet[i] * accL[fn][r]) : 0.f;
      ushort vb = f2bf(v);
      Xb[i*72 + j] = vb;
      Xt[j*72 + i] = vb;
      Pb[i*72 + j] = (i == j) ? f2bf(1.f) : vb;
    }
  __syncthreads();

  #pragma unroll 1
  for (int s = 0; s < 5; ++s){
    floatx4 accY[4];
    #pragma unroll
    for (int fn = 0; fn < 4; ++fn) accY[fn] = (floatx4)0.f;
    #pragma unroll
    for (int ks = 0; ks < 2; ++ks){
      short8 a = *(const short8*)&Xb[(w*16 + l16)*72 + ks*32 + lq*8];
      #pragma unroll
      for (int fn = 0; fn < 4; ++fn){
        short8 bb = *(const short8*)&Xt[(fn*16 + l16)*72 + ks*32 + lq*8];
        accY[fn] = mfma16(a, bb, accY[fn]);
      }
    }
    __syncthreads();
    #pragma unroll
    for (int fn = 0; fn < 4; ++fn)
      #pragma unroll
      for (int r = 0; r < 4; ++r){
        int i = w*16 + lq*4 + r, n = fn*16 + l16;
        ushort v = f2bf(accY[fn][r]);
        Xb[i*72 + n] = v;
        Xt[n*72 + i] = v;
      }
    __syncthreads();
    floatx4 accP[4];
    #pragma unroll
    for (int fn = 0; fn < 4; ++fn)
      #pragma unroll
      for (int r = 0; r < 4; ++r)
        accP[fn][r] = bf2f(Pb[(w*16 + lq*4 + r)*72 + fn*16 + l16]);
    #pragma unroll
    for (int ks = 0; ks < 2; ++ks){
      short8 a = *(const short8*)&Pb[(w*16 + l16)*72 + ks*32 + lq*8];
      #pragma unroll
      for (int fn = 0; fn < 4; ++fn){
        short8 bb = *(const short8*)&Xt[(fn*16 + l16)*72 + ks*32 + lq*8];
        accP[fn] = mfma16(a, bb, accP[fn]);
      }
    }
    #pragma unroll
    for (int fn = 0; fn < 4; ++fn)
      #pragma unroll
      for (int r = 0; r < 4; ++r)
        Pb[(w*16 + lq*4 + r)*72 + fn*16 + l16] = f2bf(accP[fn][r]);
    __syncthreads();
  }

  floatx4 accW[8], accU[8];
  #pragma unroll
  for (int fn = 0; fn < 8; ++fn){ accW[fn] = (floatx4)0.f; accU[fn] = (floatx4)0.f; }
  #pragma unroll
  for (int ks = 0; ks < 2; ++ks){
    short8 p = *(const short8*)&Pb[(w*16 + l16)*72 + ks*32 + lq*8];
    short8 a;
    #pragma unroll
    for (int e = 0; e < 8; ++e)
      a[e] = (short)f2bf(bf2f((ushort)p[e]) * bet[ks*32 + lq*8 + e]);
    #pragma unroll
    for (int fn = 0; fn < 8; ++fn){
      short8 bk = *(const short8*)&KT[(fn*16 + l16)*72 + ks*32 + lq*8];
      short8 bv = *(const short8*)&VT[(fn*16 + l16)*72 + ks*32 + lq*8];
      accW[fn] = mfma16(a, bk, accW[fn]);
      accU[fn] = mfma16(a, bv, accU[fn]);
    }
  }
  size_t base = (size_t)bx * (64 * 128);
  #pragma unroll
  for (int fn = 0; fn < 8; ++fn)
    #pragma unroll
    for (int r = 0; r < 4; ++r){
      int i = w*16 + lq*4 + r, d = fn*16 + l16;
      Wneg[base + i*128 + d] = f2bf(-accW[fn][r]);   // store -W
      U[base + i*128 + d]    = f2bf(accU[fn][r]);
    }
}

// -------- phase2 (sequential over chunks): v-split 4 ways, T14 prefetch,
// XCD co-location swizzle; Sb double-buffered -> 2 barriers/chunk.
// SAFETY (re-derived r16): staged Ws/Qs/KTc/Us slabs are WAVE-PRIVATE
// (wave w writes exactly the rows only wave w reads), so next-chunk staging
// needs no barrier vs this chunk's post-bar2 reads. Cross-wave LDS: UT
// (bar2-protected; next write after following bar1) and Sb (double-buffered).
__global__ __launch_bounds__(256) void phase2(
    const ushort* __restrict__ qn, const ushort* __restrict__ KTg,
    const ushort* __restrict__ Wneg, const ushort* __restrict__ U,
    ushort* __restrict__ UpT, ushort* __restrict__ Opart){
  __shared__ __align__(16) ushort Sb[2][32 * 136];  // S^T slice [v][k], dbuf
  __shared__ __align__(16) ushort Ws[64 * 136];
  __shared__ __align__(16) ushort Qs[64 * 136];
  __shared__ __align__(16) ushort KTc[128 * 72];
  __shared__ __align__(16) ushort Us[64 * 40];
  __shared__ __align__(16) ushort UT[32 * 72];

  const int bx = blockIdx.x;
  const int xcd = bx & 7, j = bx >> 3;
  const int bh = xcd * 4 + (j >> 2), vs = j & 3;
  const int b = bh >> 4, h = bh & 15;
  const int tid = threadIdx.x, w = tid >> 6, lane = tid & 63, l16 = lane & 15, lq = lane >> 4;

  for (int e = tid; e < 32*136; e += 256) Sb[0][e] = 0;

  floatx4 M[2][2];
  #pragma unroll
  for (int nf = 0; nf < 2; ++nf)
    #pragma unroll
    for (int kf = 0; kf < 2; ++kf) M[nf][kf] = (floatx4)0.f;

  const int si = tid >> 2, sd = (tid & 3) * 32;
  short8 rW[4], rQ[4], rK[4], rU;

  auto loadr = [&](int c){
    size_t cb = ((size_t)(bh*NC + c)) * (64 * 128);
    const ushort* wp = Wneg + cb + si*128 + sd;
    const ushort* qp = qn + ((size_t)(b*T_ + c*64 + si)) * D_ + h*DH + sd;
    const ushort* kp = KTg + cb + tid*32;
    #pragma unroll
    for (int j2 = 0; j2 < 4; ++j2){
      rW[j2] = *(const short8*)(wp + j2*8);
      rQ[j2] = *(const short8*)(qp + j2*8);
      rK[j2] = *(const short8*)(kp + j2*8);
    }
    rU = *(const short8*)(U + cb + si*128 + vs*32 + (tid & 3)*8);
  };
  loadr(0);

  for (int c = 0; c < NC; ++c){
    const ushort* Sc = &Sb[c & 1][0];        // current S^T buffer
    ushort*       Sn = &Sb[(c + 1) & 1][0];  // next buffer (rebuild target)
    #pragma unroll
    for (int j2 = 0; j2 < 4; ++j2){
      *(short8*)&Ws[si*136 + sd + j2*8] = rW[j2];
      *(short8*)&Qs[si*136 + sd + j2*8] = rQ[j2];
      *(short8*)&KTc[(tid >> 1)*72 + (tid & 1)*32 + j2*8] = rK[j2];
    }
    *(short8*)&Us[si*40 + (tid & 3)*8] = rU;
    __syncthreads();                     // bar1: stage + prev rebuild visible
    if (c + 1 < NC) loadr(c + 1);        // prefetch next chunk

    floatx4 accU[2];
    #pragma unroll
    for (int fn = 0; fn < 2; ++fn)
      #pragma unroll
      for (int r = 0; r < 4; ++r)
        accU[fn][r] = bf2f(Us[(w*16 + lq*4 + r)*40 + fn*16 + l16]);
    #pragma unroll
    for (int ks = 0; ks < 4; ++ks){
      short8 a = *(const short8*)&Ws[(w*16 + l16)*136 + ks*32 + lq*8];
      #pragma unroll
      for (int fn = 0; fn < 2; ++fn){
        short8 bs = *(const short8*)&Sc[(fn*16 + l16)*136 + ks*32 + lq*8];
        accU[fn] = mfma16(a, bs, accU[fn]);
      }
    }
    #pragma unroll
    for (int fn = 0; fn < 2; ++fn)
      #pragma unroll
      for (int r = 0; r < 4; ++r)
        UT[(fn*16 + l16)*72 + w*16 + lq*4 + r] = f2bf(accU[fn][r]);
    __syncthreads();                     // bar2: UT visible

    size_t cb = ((size_t)(bh*NC + c)) * (64 * 128);
    {
      int nl = tid >> 3, i0 = (tid & 7) * 8;
      *(short8*)(UpT + cb + (size_t)(vs*32 + nl)*64 + i0) = *(const short8*)&UT[nl*72 + i0];
    }
    floatx4 accO[2];
    #pragma unroll
    for (int fn = 0; fn < 2; ++fn) accO[fn] = (floatx4)0.f;
    #pragma unroll
    for (int ks = 0; ks < 4; ++ks){
      short8 a = *(const short8*)&Qs[(w*16 + l16)*136 + ks*32 + lq*8];
      #pragma unroll
      for (int fn = 0; fn < 2; ++fn){
        short8 bs = *(const short8*)&Sc[(fn*16 + l16)*136 + ks*32 + lq*8];
        accO[fn] = mfma16(a, bs, accO[fn]);
      }
    }
    #pragma unroll
    for (int fn = 0; fn < 2; ++fn)
      #pragma unroll
      for (int r = 0; r < 4; ++r){
        int i = w*16 + lq*4 + r;
        Opart[cb + (size_t)i*128 + vs*32 + fn*16 + l16] = f2bf(accO[fn][r]);
      }
    #pragma unroll
    for (int ks = 0; ks < 2; ++ks){
      short8 a0 = *(const short8*)&UT[(l16)*72 + ks*32 + lq*8];
      short8 a1 = *(const short8*)&UT[(16 + l16)*72 + ks*32 + lq*8];
      #pragma unroll
      for (int kf = 0; kf < 2; ++kf){
        short8 bk = *(const short8*)&KTc[(w*32 + kf*16 + l16)*72 + ks*32 + lq*8];
        M[0][kf] = mfma16(a0, bk, M[0][kf]);
        M[1][kf] = mfma16(a1, bk, M[1][kf]);
      }
    }
    // rebuild into the OTHER buffer: no barrier needed (Sn last read two
    // iterations ago; bar1/bar2 since then order all waves past those reads)
    #pragma unroll
    for (int nf = 0; nf < 2; ++nf)
      #pragma unroll
      for (int kf = 0; kf < 2; ++kf)
        #pragma unroll
        for (int r = 0; r < 4; ++r)
          Sn[(nf*16 + lq*4 + r)*136 + w*32 + kf*16 + l16] = f2bf(M[nf][kf][r]);
  }
}

// -------- phase3 (parallel): O = Opart + tril(Q K^T) U', rmsnorm, gate
__global__ __launch_bounds__(256) void phase3(
    const ushort* __restrict__ qn, const ushort* __restrict__ kn,
    const ushort* __restrict__ UpT, const ushort* __restrict__ Opart,
    const ushort* g, const float* __restrict__ norm_w,
    ushort* og){
  __shared__ __align__(16) ushort Qs[64 * 136];
  __shared__ __align__(16) ushort Ks[64 * 136];
  __shared__ __align__(16) ushort UTs[128 * 72];
  __shared__ __align__(16) ushort Os[64 * 136];
  __shared__ __align__(16) ushort Gs[64 * 136];
  __shared__ __align__(16) ushort Ab[64 * 72];
  __shared__ float nw[128];

  const int bx = blockIdx.x;
  const int c = bx & 63, h = (bx >> 6) & 15, b = bx >> 10;
  const int t0 = c * 64;
  const int tid = threadIdx.x, w = tid >> 6, lane = tid & 63, l16 = lane & 15, lq = lane >> 4;
  const size_t cb = (size_t)bx * (64 * 128);

  {
    int i = tid >> 2, d0 = (tid & 3) * 32;
    const ushort* qp = qn + (size_t)(b*T_ + t0 + i) * D_ + h*DH + d0;
    const ushort* kp = kn + (size_t)(b*T_ + t0 + i) * D_ + h*DH + d0;
    const ushort* gp = g  + (size_t)(b*T_ + t0 + i) * D_ + h*DH + d0;
    const ushort* op = Opart + cb + i*128 + d0;
    #pragma unroll
    for (int j = 0; j < 4; ++j){
      *(short8*)&Qs[i*136 + d0 + j*8] = *(const short8*)(qp + j*8);
      *(short8*)&Ks[i*136 + d0 + j*8] = *(const short8*)(kp + j*8);
      *(short8*)&Gs[i*136 + d0 + j*8] = *(const short8*)(gp + j*8);
      *(short8*)&Os[i*136 + d0 + j*8] = *(const short8*)(op + j*8);
    }
    int n = tid >> 1, i0 = (tid & 1) * 32;
    #pragma unroll
    for (int j = 0; j < 4; ++j)
      *(short8*)&UTs[n*72 + i0 + j*8] = *(const short8*)(UpT + cb + n*64 + i0 + j*8);
    if (tid < 128) nw[tid] = norm_w[tid];
  }
  __syncthreads();

  floatx4 accA[4];
  #pragma unroll
  for (int fn = 0; fn < 4; ++fn) accA[fn] = (floatx4)0.f;
  #pragma unroll
  for (int ks = 0; ks < 4; ++ks){
    short8 a = *(const short8*)&Qs[(w*16 + l16)*136 + ks*32 + lq*8];
    #pragma unroll
    for (int fn = 0; fn < 4; ++fn){
      short8 bb = *(const short8*)&Ks[(fn*16 + l16)*136 + ks*32 + lq*8];
      accA[fn] = mfma16(a, bb, accA[fn]);
    }
  }
  #pragma unroll
  for (int fn = 0; fn < 4; ++fn)
    #pragma unroll
    for (int r = 0; r < 4; ++r){
      int i = w*16 + lq*4 + r, j = fn*16 + l16;
      Ab[i*72 + j] = f2bf((j <= i) ? accA[fn][r] : 0.f);
    }
  __syncthreads();

  floatx4 accO[8];
  #pragma unroll
  for (int fn = 0; fn < 8; ++fn)
    #pragma unroll
    for (int r = 0; r < 4; ++r)
      accO[fn][r] = bf2f(Os[(w*16 + lq*4 + r)*136 + fn*16 + l16]);
  #pragma unroll
  for (int ks = 0; ks < 2; ++ks){
    short8 a = *(const short8*)&Ab[(w*16 + l16)*72 + ks*32 + lq*8];
    #pragma unroll
    for (int fn = 0; fn < 8; ++fn){
      short8 bu = *(const short8*)&UTs[(fn*16 + l16)*72 + ks*32 + lq*8];
      accO[fn] = mfma16(a, bu, accO[fn]);
    }
  }
  #pragma unroll
  for (int r = 0; r < 4; ++r){
    float ss = 0.f;
    #pragma unroll
    for (int fn = 0; fn < 8; ++fn) ss += accO[fn][r] * accO[fn][r];
    #pragma unroll
    for (int m = 1; m < 16; m <<= 1) ss += __shfl_xor(ss, m);
    float rms = rsqrtf(ss * (1.f / 128.f) + 1e-5f);
    int i = w*16 + lq*4 + r;
    #pragma unroll
    for (int fn = 0; fn < 8; ++fn){
      int d = fn*16 + l16;
      float gv = bf2f(Gs[i*136 + d]);
      float o = accO[fn][r] * rms * nw[d] * sigm(gv);
      og[(size_t)(b*T_ + t0 + i) * D_ + h*DH + d] = f2bf(o);
    }
  }
}

// ---------------------------------------------------------------- launcher
extern "C" void kernel_launch(void* const* d_in, const int* in_sizes, int n_in,
                              void* d_out, int out_size, void* d_ws, size_t ws_size,
                              hipStream_t stream){
  const float* hidden = (const float*)d_in[0];
  const float* Wq = (const float*)d_in[5];
  const float* Wk = (const float*)d_in[6];
  const float* Wv = (const float*)d_in[7];
  const float* Wo = (const float*)d_in[8];
  const float* Wg = (const float*)d_in[9];
  const float* Wb = (const float*)d_in[10];
  const float* cwq = (const float*)d_in[11];
  const float* cwk = (const float*)d_in[12];
  const float* cwv = (const float*)d_in[13];
  const float* nw  = (const float*)d_in[14];

  char* ws = (char*)d_ws;
  size_t off = 0;
  auto alloc = [&](size_t bytes){ void* p = ws + off; off += (bytes + 255) & ~(size_t)255; return p; };
  const size_t SZ = (size_t)BT * D_ * 2;          // 32 MiB bf16 tensor
  ushort* hb   = (ushort*)alloc(SZ);              // hidden bf16 -> Opart
  ushort* wqT  = (ushort*)alloc((size_t)D_*D_*2); // wqT|wkT|wvT contiguous = fused B
  ushort* wkT  = (ushort*)alloc((size_t)D_*D_*2);
  ushort* wvT  = (ushort*)alloc((size_t)D_*D_*2);
  ushort* wgT  = (ushort*)alloc((size_t)D_*D_*2);
  ushort* woT  = (ushort*)alloc((size_t)D_*D_*2);
  ushort* wbT  = (ushort*)alloc((size_t)H_*D_*2);
  ushort* fqkv = (ushort*)alloc(3*SZ);            // fused [BT][3D] -> gpre|Wneg|U
  ushort* kn   = (ushort*)alloc(SZ);
  ushort* vcv  = (ushort*)alloc(SZ);              // -> UpT after phase1
  float*  beta = (float*)alloc((size_t)BT * H_ * 4);
  (void)in_sizes; (void)n_in; (void)out_size;
  if (off > ws_size) return;                      // ws too small -> clean absmax fail

  // d_out (64 MiB f32): first half = bf16 qn scratch, second half = KTg.
  ushort* qn  = (ushort*)d_out;
  ushort* KTg = (ushort*)d_out + (size_t)BT * D_;

  cast_bf16_kernel<<<8192, 256, 0, stream>>>(hidden, hb, BT * D_);
  transpose_cast5<<<dim3(64, 64, 5), 256, 0, stream>>>(Wq, Wk, Wv, Wg, Wo,
                                                       wqT, wkT, wvT, wgT, woT);
  cast_wbT<<<D_/256, 256, 0, stream>>>(Wb, wbT);

  // Fused QKV projection: C[8192][6144] = hb @ [wqT;wkT;wvT]^T
  {
    const int NWG = (BT / 256) * (RSQ / 256);     // 768 (cpx=96, rect 8x12)
    gemm256k<false><<<NWG, 512, 0, stream>>>(hb, wqT, fqkv, BT, RSQ, D_);
  }

  conv3_kernel<<<BT/8, 256, 0, stream>>>(fqkv, cwq, cwk, cwv, qn, kn, vcv);
  beta_kernel<<<BT/4, 256, 0, stream>>>(hb, wbT, beta);

  // fqkv fully dead after conv: reuse as gpre | Wneg | U
  ushort* gpre = fqkv;
  ushort* Wneg = fqkv + (size_t)BT * D_;
  ushort* Ubuf = fqkv + (size_t)2 * BT * D_;
  {
    const int NWG = (BT / 256) * (D_ / 256);      // 256 (cpx=32, rect 8x4)
    gemm256k<false><<<NWG, 512, 0, stream>>>(hb, wgT, gpre, BT, D_, D_);
  }

  ushort* Opart = hb;     // dead after proj GEMMs

  phase1<<<B_ * H_ * NC, 256, 0, stream>>>(kn, vcv, beta, Wneg, Ubuf, KTg);
  ushort* UpT = vcv;      // vcv dead after phase1
  phase2<<<B_ * H_ * 4, 256, 0, stream>>>(qn, KTg, Wneg, Ubuf, UpT, Opart);
  ushort* og = gpre;      // in-place gate (block reads its g-tile to LDS first)
  phase3<<<B_ * H_ * NC, 256, 0, stream>>>(qn, kn, UpT, Opart, gpre, nw, og);

  {
    const int NWG = (BT / 256) * (D_ / 256);      // 256 (cpx=32, rect 8x4)
    gemm256k<true><<<NWG, 512, 0, stream>>>(og, woT, (float*)d_out, BT, D_, D_);
  }
}